// Round 5
// baseline (363.788 us; speedup 1.0000x reference)
//
#include <hip/hip_runtime.h>

// Problem constants (B=4, S=4096, D_MODEL=1024, H*Dk=H*Dv=1024)
#define M_TOT 16384
#define DM    1024
#define KTILES 32          // K = 1024, BK = 32

typedef unsigned short ushort_t;
typedef __bf16 bf16x8 __attribute__((ext_vector_type(8)));
typedef float  f32x4  __attribute__((ext_vector_type(4)));

__device__ __forceinline__ ushort_t f32_to_bf16(float f) {
    union { float f; unsigned u; } v; v.f = f;
    unsigned u = v.u;
    return (ushort_t)((u + 0x7fffu + ((u >> 16) & 1u)) >> 16);   // RNE
}
__device__ __forceinline__ float bf16_to_f32(ushort_t h) {
    union { unsigned u; float f; } v; v.u = ((unsigned)h) << 16;
    return v.f;
}

// Swizzled LDS chunk offset (ushorts) for global chunk c of a row-major
// (rows x 32) bf16 tile: row=c>>2, pos=(c&3)^((row>>1)&3). r2/r3 verified:
// zero bank conflicts read+write.
__device__ __forceinline__ int sw_off(int c) {
    return ((c >> 2) << 5) + ((((c & 3) ^ ((c >> 3) & 3))) << 3);
}

// ---------------- fused fp32 -> bf16 conversion (x + 3 weights) ----------------
__global__ __launch_bounds__(256) void cvt_all(const float* __restrict__ x,
                                               const float* __restrict__ wv,
                                               const float* __restrict__ wg,
                                               const float* __restrict__ wo,
                                               ushort_t* __restrict__ xb,
                                               ushort_t* __restrict__ wvb,
                                               ushort_t* __restrict__ wgb,
                                               ushort_t* __restrict__ wob) {
    const long NX = (long)M_TOT * DM / 4, NW = (long)DM * DM / 4;
    long i = (long)blockIdx.x * 256 + threadIdx.x;     // float4 index
    const float* src; ushort_t* dst; long off;
    if (i < NX)               { src = x;  dst = xb;  off = i; }
    else if (i < NX + NW)     { src = wv; dst = wvb; off = i - NX; }
    else if (i < NX + 2 * NW) { src = wg; dst = wgb; off = i - NX - NW; }
    else                      { src = wo; dst = wob; off = i - NX - 2 * NW; }
    const float4 v = ((const float4*)src)[off];
    ushort4 o;
    o.x = f32_to_bf16(v.x); o.y = f32_to_bf16(v.y);
    o.z = f32_to_bf16(v.z); o.w = f32_to_bf16(v.w);
    ((ushort4*)dst)[off] = o;
}

// ---------------- GEMM1: V & g, shared A, fused silu-gate ----------------
// Block tile 128x64, wave tile 64x32, dual acc. A-fragments loaded DIRECTLY
// from global (register prefetch, no LDS); B (Wv,Wg) LDS double-buffered.
// XCD swizzle: flat&7 = XCD; all 16 n-blocks of an m-block share an XCD.
__global__ __launch_bounds__(256, 4) void gemm_vg(
    const ushort_t* __restrict__ A,
    const ushort_t* __restrict__ Wv,
    const ushort_t* __restrict__ Wg,
    ushort_t* __restrict__ gated)
{
    __shared__ __align__(16) ushort_t Bvs[2 * 2048];  // 8 KB (64x32 x2)
    __shared__ __align__(16) ushort_t Bgs[2 * 2048];  // 8 KB

    const int flat = blockIdx.x;
    const int g   = flat & 7;
    const int t   = flat >> 3;           // [0,256)
    const int n0  = (t & 15) * 64;
    const int m0  = (((t >> 4) << 3) | g) * 128;

    const int tid  = threadIdx.x;
    const int wave = tid >> 6;
    const int lane = tid & 63;

    f32x4 accv[4][2], accg[4][2];
    const f32x4 vzero = {0.f, 0.f, 0.f, 0.f};
#pragma unroll
    for (int i = 0; i < 4; ++i)
#pragma unroll
        for (int j = 0; j < 2; ++j) { accv[i][j] = vzero; accg[i][j] = vzero; }

    // B staging: tile = 256 chunks (64 rows x 32 k). Threads 0-127 stage Wv,
    // threads 128-255 stage Wg; each thread stages 2 chunks (cB, cB+128).
    const int cB0 = tid & 127, cB1 = cB0 + 128;
    const ushort_t* Wsrc = (tid & 128) ? Wg : Wv;
    ushort_t* Bbase = (tid & 128) ? Bgs : Bvs;
    const long gB0 = (long)(n0 + (cB0 >> 2)) * DM + ((cB0 & 3) << 3);
    const long gB1 = (long)(n0 + (cB1 >> 2)) * DM + ((cB1 & 3) << 3);
    const int wB0 = sw_off(cB0), wB1 = sw_off(cB1);

    // fragment addressing
    const int fr   = lane & 15;
    const int quad = lane >> 4;
    const int sw   = ((quad ^ ((fr >> 1) & 3)) << 3);
    const int wmBase = (wave >> 1) * 64;
    const int wnBase = (wave & 1) * 32;
    const long aBase = (long)(m0 + wmBase + fr) * DM + (quad << 3);
    int rdB[2];
#pragma unroll
    for (int j = 0; j < 2; ++j) rdB[j] = (wnBase + j * 16 + fr) * 32 + sw;

    bf16x8 curA[4], nxtA[4];
    auto compute = [&](const ushort_t* pv, const ushort_t* pg) {
#pragma unroll
        for (int j = 0; j < 2; ++j) {
            bf16x8 bv = *(const bf16x8*)(pv + rdB[j]);
            bf16x8 bg = *(const bf16x8*)(pg + rdB[j]);
#pragma unroll
            for (int i = 0; i < 4; ++i) {
                accv[i][j] = __builtin_amdgcn_mfma_f32_16x16x32_bf16(curA[i], bv, accv[i][j], 0, 0, 0);
                accg[i][j] = __builtin_amdgcn_mfma_f32_16x16x32_bf16(curA[i], bg, accg[i][j], 0, 0, 0);
            }
        }
    };

    // prologue: tile 0
    int4 rB0 = *(const int4*)(Wsrc + gB0);
    int4 rB1 = *(const int4*)(Wsrc + gB1);
#pragma unroll
    for (int i = 0; i < 4; ++i)
        curA[i] = *(const bf16x8*)(A + aBase + (long)i * 16 * DM);
    unsigned xb = 0;
    *(int4*)(Bbase + xb + wB0) = rB0;
    *(int4*)(Bbase + xb + wB1) = rB1;
    __syncthreads();

    for (int kt = 0; kt < KTILES - 1; ++kt) {
        const int k0 = (kt + 1) * 32;
#pragma unroll
        for (int i = 0; i < 4; ++i)
            nxtA[i] = *(const bf16x8*)(A + aBase + (long)i * 16 * DM + k0);
        rB0 = *(const int4*)(Wsrc + gB0 + k0);
        rB1 = *(const int4*)(Wsrc + gB1 + k0);
        compute(Bvs + xb, Bgs + xb);
        xb ^= 2048;
        *(int4*)(Bbase + xb + wB0) = rB0;
        *(int4*)(Bbase + xb + wB1) = rB1;
        __syncthreads();
#pragma unroll
        for (int i = 0; i < 4; ++i) curA[i] = nxtA[i];
    }
    compute(Bvs + xb, Bgs + xb);

    // epilogue: gated = V * silu(g); C/D layout: col=lane&15, row=quad*4+reg
#pragma unroll
    for (int i = 0; i < 4; ++i) {
#pragma unroll
        for (int j = 0; j < 2; ++j) {
            const int colg = n0 + wnBase + j * 16 + fr;
#pragma unroll
            for (int r = 0; r < 4; ++r) {
                const int rowg = m0 + wmBase + i * 16 + quad * 4 + r;
                float v = accv[i][j][r];
                float gg = accg[i][j][r];
                float gate = gg / (1.0f + __expf(-gg));   // silu
                gated[rowg * DM + colg] = f32_to_bf16(v * gate);
            }
        }
    }
}

// ---------------- GEMM2: proj = gated @ Wo^T, + bf16 residual, store pre ----------------
// Block tile 128x128, wave tile 64x64. Same direct-global-A structure.
__global__ __launch_bounds__(256, 4) void gemm_o(
    const ushort_t* __restrict__ A,    // gated bf16 [16384,1024]
    const ushort_t* __restrict__ Wo,   // [1024,1024] bf16 [out,in]
    const ushort_t* __restrict__ Xb,   // residual bf16 [16384,1024]
    ushort_t* __restrict__ preout)     // pre = proj + x (may alias Xb)
{
    __shared__ __align__(16) ushort_t Bs[2 * 4096];   // 16 KB (128x32 x2)

    const int flat = blockIdx.x;
    const int g   = flat & 7;
    const int t   = flat >> 3;           // [0,128)
    const int n0  = (t & 7) * 128;
    const int m0  = (((t >> 3) << 3) | g) * 128;

    const int tid  = threadIdx.x;
    const int wave = tid >> 6;
    const int lane = tid & 63;

    f32x4 acc[4][4];
    const f32x4 vzero = {0.f, 0.f, 0.f, 0.f};
#pragma unroll
    for (int i = 0; i < 4; ++i)
#pragma unroll
        for (int j = 0; j < 4; ++j) acc[i][j] = vzero;

    // B staging: 512 chunks, thread stages chunks tid and tid+256
    const int cB0 = tid, cB1 = tid + 256;
    const long gB0 = (long)(n0 + (cB0 >> 2)) * DM + ((cB0 & 3) << 3);
    const long gB1 = (long)(n0 + (cB1 >> 2)) * DM + ((cB1 & 3) << 3);
    const int wB0 = sw_off(cB0), wB1 = sw_off(cB1);

    const int fr   = lane & 15;
    const int quad = lane >> 4;
    const int sw   = ((quad ^ ((fr >> 1) & 3)) << 3);
    const int wmBase = (wave >> 1) * 64;
    const int wnBase = (wave & 1) * 64;
    const long aBase = (long)(m0 + wmBase + fr) * DM + (quad << 3);
    int rdB[4];
#pragma unroll
    for (int j = 0; j < 4; ++j) rdB[j] = (wnBase + j * 16 + fr) * 32 + sw;

    bf16x8 curA[4], nxtA[4];
    auto compute = [&](const ushort_t* pb) {
#pragma unroll
        for (int j = 0; j < 4; ++j) {
            bf16x8 bw = *(const bf16x8*)(pb + rdB[j]);
#pragma unroll
            for (int i = 0; i < 4; ++i)
                acc[i][j] = __builtin_amdgcn_mfma_f32_16x16x32_bf16(curA[i], bw, acc[i][j], 0, 0, 0);
        }
    };

    int4 rB0 = *(const int4*)(Wo + gB0);
    int4 rB1 = *(const int4*)(Wo + gB1);
#pragma unroll
    for (int i = 0; i < 4; ++i)
        curA[i] = *(const bf16x8*)(A + aBase + (long)i * 16 * DM);
    unsigned xb = 0;
    *(int4*)(Bs + xb + wB0) = rB0;
    *(int4*)(Bs + xb + wB1) = rB1;
    __syncthreads();

    for (int kt = 0; kt < KTILES - 1; ++kt) {
        const int k0 = (kt + 1) * 32;
#pragma unroll
        for (int i = 0; i < 4; ++i)
            nxtA[i] = *(const bf16x8*)(A + aBase + (long)i * 16 * DM + k0);
        rB0 = *(const int4*)(Wo + gB0 + k0);
        rB1 = *(const int4*)(Wo + gB1 + k0);
        compute(Bs + xb);
        xb ^= 4096;
        *(int4*)(Bs + xb + wB0) = rB0;
        *(int4*)(Bs + xb + wB1) = rB1;
        __syncthreads();
#pragma unroll
        for (int i = 0; i < 4; ++i) curA[i] = nxtA[i];
    }
    compute(Bs + xb);

    // epilogue: pre = proj + x(bf16); in-place safe (each elem: one thread, read-before-write)
#pragma unroll
    for (int i = 0; i < 4; ++i) {
#pragma unroll
        for (int j = 0; j < 4; ++j) {
            const int colg = n0 + wnBase + j * 16 + fr;
#pragma unroll
            for (int r = 0; r < 4; ++r) {
                const int rowg = m0 + wmBase + i * 16 + quad * 4 + r;
                float pre = acc[i][j][r] + bf16_to_f32(Xb[rowg * DM + colg]);
                preout[rowg * DM + colg] = f32_to_bf16(pre);
            }
        }
    }
}

// ---------------- LayerNorm over rows of 1024 ----------------
__global__ __launch_bounds__(256) void ln_rows(const ushort_t* __restrict__ pre,
                                               const float* __restrict__ gamma,
                                               const float* __restrict__ beta,
                                               float* __restrict__ out)
{
    const int row = blockIdx.x;
    const int tid = threadIdx.x;
    const int wave = tid >> 6, lane = tid & 63;

    ushort4 u = ((const ushort4*)(pre + row * DM))[tid];
    float p0 = bf16_to_f32(u.x), p1 = bf16_to_f32(u.y);
    float p2 = bf16_to_f32(u.z), p3 = bf16_to_f32(u.w);

    float s  = p0 + p1 + p2 + p3;
    float ss = p0 * p0 + p1 * p1 + p2 * p2 + p3 * p3;
#pragma unroll
    for (int off = 32; off > 0; off >>= 1) {
        s  += __shfl_down(s, off);
        ss += __shfl_down(ss, off);
    }
    __shared__ float red[8];
    __shared__ float mb[2];
    if (lane == 0) { red[wave] = s; red[4 + wave] = ss; }
    __syncthreads();
    if (tid == 0) {
        float S  = red[0] + red[1] + red[2] + red[3];
        float SS = red[4] + red[5] + red[6] + red[7];
        float mean = S * (1.0f / 1024.0f);
        float var  = SS * (1.0f / 1024.0f) - mean * mean;
        mb[0] = mean;
        mb[1] = rsqrtf(var + 1e-5f);
    }
    __syncthreads();
    const float mean = mb[0], rs = mb[1];

    float4 gm = ((const float4*)gamma)[tid];
    float4 bt = ((const float4*)beta)[tid];
    float4 o;
    o.x = (p0 - mean) * rs * gm.x + bt.x;
    o.y = (p1 - mean) * rs * gm.y + bt.y;
    o.z = (p2 - mean) * rs * gm.z + bt.z;
    o.w = (p3 - mean) * rs * gm.w + bt.w;
    ((float4*)(out + row * DM))[tid] = o;
}

// ---------------- launch ----------------
extern "C" void kernel_launch(void* const* d_in, const int* in_sizes, int n_in,
                              void* d_out, int out_size, void* d_ws, size_t ws_size,
                              hipStream_t stream) {
    // setup_inputs order: x, W_Q, W_K, W_V, W_g, W_alpha, W_O, ln_gamma, ln_beta
    const float* x     = (const float*)d_in[0];
    const float* WV    = (const float*)d_in[3];
    const float* WG    = (const float*)d_in[4];
    const float* WO    = (const float*)d_in[6];
    const float* gamma = (const float*)d_in[7];
    const float* beta  = (const float*)d_in[8];
    float* out = (float*)d_out;

    // ws layout: [0,32MB): x_bf16 (later aliased as pre) | [32,64MB): gated | [64MB..): weights bf16
    char* ws = (char*)d_ws;
    ushort_t* xb    = (ushort_t*)ws;
    ushort_t* gated = (ushort_t*)(ws + (size_t)M_TOT * DM * 2);
    ushort_t* wvb   = (ushort_t*)(ws + (size_t)M_TOT * DM * 4);
    ushort_t* wgb   = (ushort_t*)(ws + (size_t)M_TOT * DM * 4 + (size_t)DM * DM * 2);
    ushort_t* wob   = (ushort_t*)(ws + (size_t)M_TOT * DM * 4 + (size_t)DM * DM * 4);
    ushort_t* pre   = xb;  // alias: in-place residual+store in gemm_o

    const int nCvt = (M_TOT * DM + 3 * DM * DM) / 4 / 256;
    cvt_all<<<nCvt, 256, 0, stream>>>(x, WV, WG, WO, xb, wvb, wgb, wob);

    gemm_vg<<<2048, 256, 0, stream>>>(xb, wvb, wgb, gated);
    gemm_o <<<1024, 256, 0, stream>>>(gated, wob, xb, pre);
    ln_rows<<<M_TOT, 256, 0, stream>>>(pre, gamma, beta, out);
}

// Round 6
// 286.507 us; speedup vs baseline: 1.2697x; 1.2697x over previous
//
#include <hip/hip_runtime.h>

// Problem constants (B=4, S=4096, D_MODEL=1024, H*Dk=H*Dv=1024)
#define M_TOT 16384
#define DM    1024
#define KTILES 32          // K = 1024, BK = 32

typedef unsigned short ushort_t;
typedef __bf16 bf16x8 __attribute__((ext_vector_type(8)));
typedef float  f32x4  __attribute__((ext_vector_type(4)));

__device__ __forceinline__ ushort_t f32_to_bf16(float f) {
    union { float f; unsigned u; } v; v.f = f;
    unsigned u = v.u;
    return (ushort_t)((u + 0x7fffu + ((u >> 16) & 1u)) >> 16);   // RNE
}
__device__ __forceinline__ float bf16_to_f32(ushort_t h) {
    union { unsigned u; float f; } v; v.u = ((unsigned)h) << 16;
    return v.f;
}

// Swizzled LDS chunk offset (ushorts) for global chunk c of a row-major
// (rows x 32) bf16 tile: row=c>>2, pos=(c&3)^((row>>1)&3). r2/r3 verified:
// zero bank conflicts read+write.
__device__ __forceinline__ int sw_off(int c) {
    return ((c >> 2) << 5) + ((((c & 3) ^ ((c >> 3) & 3))) << 3);
}

// ---------------- fused fp32 -> bf16 conversion (x + 3 weights) ----------------
__global__ __launch_bounds__(256) void cvt_all(const float* __restrict__ x,
                                               const float* __restrict__ wv,
                                               const float* __restrict__ wg,
                                               const float* __restrict__ wo,
                                               ushort_t* __restrict__ xb,
                                               ushort_t* __restrict__ wvb,
                                               ushort_t* __restrict__ wgb,
                                               ushort_t* __restrict__ wob) {
    const long NX = (long)M_TOT * DM / 4, NW = (long)DM * DM / 4;
    long i = (long)blockIdx.x * 256 + threadIdx.x;     // float4 index
    const float* src; ushort_t* dst; long off;
    if (i < NX)               { src = x;  dst = xb;  off = i; }
    else if (i < NX + NW)     { src = wv; dst = wvb; off = i - NX; }
    else if (i < NX + 2 * NW) { src = wg; dst = wgb; off = i - NX - NW; }
    else                      { src = wo; dst = wob; off = i - NX - 2 * NW; }
    const float4 v = ((const float4*)src)[off];
    ushort4 o;
    o.x = f32_to_bf16(v.x); o.y = f32_to_bf16(v.y);
    o.z = f32_to_bf16(v.z); o.w = f32_to_bf16(v.w);
    ((ushort4*)dst)[off] = o;
}

// ---------------- GEMM1: V & g with shared A-tile, fused silu-gate ----------------
// Block tile 128x64, wave tile 64x32, dual accumulators. r3 pipeline:
// global->VGPR prefetch, LDS double-buffer (A and B both staged), 1 barrier/iter.
// XCD swizzle: flat&7 = XCD; all 16 n-blocks of an m-slab share an XCD.
__global__ __launch_bounds__(256, 3) void gemm_vg(
    const ushort_t* __restrict__ A,
    const ushort_t* __restrict__ Wv,
    const ushort_t* __restrict__ Wg,
    ushort_t* __restrict__ gated)
{
    __shared__ __align__(16) ushort_t As[2 * 4096];   // 16 KB (128x32 x2)
    __shared__ __align__(16) ushort_t Bvs[2 * 2048];  //  8 KB (64x32 x2)
    __shared__ __align__(16) ushort_t Bgs[2 * 2048];  //  8 KB

    const int flat = blockIdx.x;
    const int g   = flat & 7;
    const int t   = flat >> 3;           // [0,256)
    const int n0  = (t & 15) * 64;
    const int m0  = (((t >> 4) << 3) | g) * 128;

    const int tid  = threadIdx.x;
    const int wave = tid >> 6;
    const int lane = tid & 63;

    f32x4 accv[4][2], accg[4][2];
    const f32x4 vzero = {0.f, 0.f, 0.f, 0.f};
#pragma unroll
    for (int i = 0; i < 4; ++i)
#pragma unroll
        for (int j = 0; j < 2; ++j) { accv[i][j] = vzero; accg[i][j] = vzero; }

    // staging: per-thread 2 A chunks + 1 Wv chunk + 1 Wg chunk (16 B each)
    const int cA0 = wave * 128 + lane, cA1 = cA0 + 64;
    const int cB  = wave * 64 + lane;
    const long gA0 = (long)(m0 + (cA0 >> 2)) * DM + ((cA0 & 3) << 3);
    const long gA1 = (long)(m0 + (cA1 >> 2)) * DM + ((cA1 & 3) << 3);
    const long gB  = (long)(n0 + (cB  >> 2)) * DM + ((cB  & 3) << 3);
    const int wA0 = sw_off(cA0), wA1 = sw_off(cA1), wB = sw_off(cB);

    // fragment read offsets
    const int fr   = lane & 15;
    const int quad = lane >> 4;
    const int sw   = ((quad ^ ((fr >> 1) & 3)) << 3);
    const int wmBase = (wave >> 1) * 64;
    const int wnBase = (wave & 1) * 32;
    int rdA[4], rdB[2];
#pragma unroll
    for (int i = 0; i < 4; ++i) rdA[i] = (wmBase + i * 16 + fr) * 32 + sw;
#pragma unroll
    for (int j = 0; j < 2; ++j) rdB[j] = (wnBase + j * 16 + fr) * 32 + sw;

    auto compute = [&](const ushort_t* pa, const ushort_t* pv, const ushort_t* pg) {
        bf16x8 af[4];
#pragma unroll
        for (int i = 0; i < 4; ++i) af[i] = *(const bf16x8*)(pa + rdA[i]);
#pragma unroll
        for (int j = 0; j < 2; ++j) {
            bf16x8 bv = *(const bf16x8*)(pv + rdB[j]);
            bf16x8 bg = *(const bf16x8*)(pg + rdB[j]);
#pragma unroll
            for (int i = 0; i < 4; ++i) {
                accv[i][j] = __builtin_amdgcn_mfma_f32_16x16x32_bf16(af[i], bv, accv[i][j], 0, 0, 0);
                accg[i][j] = __builtin_amdgcn_mfma_f32_16x16x32_bf16(af[i], bg, accg[i][j], 0, 0, 0);
            }
        }
    };

    // prologue: tile 0
    int4 rA0 = *(const int4*)(A + gA0);
    int4 rA1 = *(const int4*)(A + gA1);
    int4 rV  = *(const int4*)(Wv + gB);
    int4 rG  = *(const int4*)(Wg + gB);
    unsigned xa = 0, xb = 0;
    *(int4*)(As + xa + wA0)  = rA0;
    *(int4*)(As + xa + wA1)  = rA1;
    *(int4*)(Bvs + xb + wB)  = rV;
    *(int4*)(Bgs + xb + wB)  = rG;
    __syncthreads();

    for (int kt = 0; kt < KTILES - 1; ++kt) {
        const int k0 = (kt + 1) * 32;
        rA0 = *(const int4*)(A + gA0 + k0);       // prefetch next tile (no barrier dep)
        rA1 = *(const int4*)(A + gA1 + k0);
        rV  = *(const int4*)(Wv + gB + k0);
        rG  = *(const int4*)(Wg + gB + k0);
        compute(As + xa, Bvs + xb, Bgs + xb);     // MFMA on current buffer
        xa ^= 4096; xb ^= 2048;
        *(int4*)(As + xa + wA0)  = rA0;           // vmcnt wait lands here, after MFMAs
        *(int4*)(As + xa + wA1)  = rA1;
        *(int4*)(Bvs + xb + wB)  = rV;
        *(int4*)(Bgs + xb + wB)  = rG;
        __syncthreads();                          // drains lgkm only
    }
    compute(As + xa, Bvs + xb, Bgs + xb);

    // epilogue: gated = V * silu(g); C/D layout: col=lane&15, row=quad*4+reg
#pragma unroll
    for (int i = 0; i < 4; ++i) {
#pragma unroll
        for (int j = 0; j < 2; ++j) {
            const int colg = n0 + wnBase + j * 16 + fr;
#pragma unroll
            for (int r = 0; r < 4; ++r) {
                const int rowg = m0 + wmBase + i * 16 + quad * 4 + r;
                float v = accv[i][j][r];
                float gg = accg[i][j][r];
                float gate = gg / (1.0f + __expf(-gg));   // silu
                gated[rowg * DM + colg] = f32_to_bf16(v * gate);
            }
        }
    }
}

// ---------------- GEMM2: proj = gated @ Wo^T, + bf16 residual, store pre ----------------
// Block tile 128x128, wave tile 64x64, r3 pipelined structure + XCD swizzle.
__global__ __launch_bounds__(256, 3) void gemm_o(
    const ushort_t* __restrict__ A,    // gated bf16 [16384,1024]
    const ushort_t* __restrict__ Wo,   // [1024,1024] bf16 [out,in]
    const ushort_t* __restrict__ Xb,   // residual bf16 [16384,1024]
    ushort_t* __restrict__ preout)     // pre = proj + x (aliases Xb; in-place safe)
{
    __shared__ __align__(16) ushort_t As[2 * 4096];   // 16 KB
    __shared__ __align__(16) ushort_t Bs[2 * 4096];   // 16 KB

    const int flat = blockIdx.x;
    const int g   = flat & 7;
    const int t   = flat >> 3;           // [0,128)
    const int n0  = (t & 7) * 128;
    const int m0  = (((t >> 3) << 3) | g) * 128;

    const int tid  = threadIdx.x;
    const int wave = tid >> 6;
    const int lane = tid & 63;

    f32x4 acc[4][4];
    const f32x4 vzero = {0.f, 0.f, 0.f, 0.f};
#pragma unroll
    for (int i = 0; i < 4; ++i)
#pragma unroll
        for (int j = 0; j < 4; ++j) acc[i][j] = vzero;

    const int cA0 = wave * 128 + lane, cA1 = cA0 + 64;
    const long gA0 = (long)(m0 + (cA0 >> 2)) * DM + ((cA0 & 3) << 3);
    const long gA1 = (long)(m0 + (cA1 >> 2)) * DM + ((cA1 & 3) << 3);
    const long gB0 = (long)(n0 + (cA0 >> 2)) * DM + ((cA0 & 3) << 3);
    const long gB1 = (long)(n0 + (cA1 >> 2)) * DM + ((cA1 & 3) << 3);
    const int wA0 = sw_off(cA0), wA1 = sw_off(cA1);

    const int fr   = lane & 15;
    const int quad = lane >> 4;
    const int sw   = ((quad ^ ((fr >> 1) & 3)) << 3);
    const int wmBase = (wave >> 1) * 64;
    const int wnBase = (wave & 1) * 64;
    int rdA[4], rdB[4];
#pragma unroll
    for (int i = 0; i < 4; ++i) rdA[i] = (wmBase + i * 16 + fr) * 32 + sw;
#pragma unroll
    for (int j = 0; j < 4; ++j) rdB[j] = (wnBase + j * 16 + fr) * 32 + sw;

    auto compute = [&](const ushort_t* pa, const ushort_t* pb) {
        bf16x8 af[4];
#pragma unroll
        for (int i = 0; i < 4; ++i) af[i] = *(const bf16x8*)(pa + rdA[i]);
#pragma unroll
        for (int j = 0; j < 4; ++j) {
            bf16x8 bw = *(const bf16x8*)(pb + rdB[j]);
#pragma unroll
            for (int i = 0; i < 4; ++i)
                acc[i][j] = __builtin_amdgcn_mfma_f32_16x16x32_bf16(af[i], bw, acc[i][j], 0, 0, 0);
        }
    };

    int4 rA0 = *(const int4*)(A + gA0);
    int4 rA1 = *(const int4*)(A + gA1);
    int4 rB0 = *(const int4*)(Wo + gB0);
    int4 rB1 = *(const int4*)(Wo + gB1);
    unsigned xa = 0;
    *(int4*)(As + xa + wA0) = rA0;
    *(int4*)(As + xa + wA1) = rA1;
    *(int4*)(Bs + xa + wA0) = rB0;
    *(int4*)(Bs + xa + wA1) = rB1;
    __syncthreads();

    for (int kt = 0; kt < KTILES - 1; ++kt) {
        const int k0 = (kt + 1) * 32;
        rA0 = *(const int4*)(A + gA0 + k0);
        rA1 = *(const int4*)(A + gA1 + k0);
        rB0 = *(const int4*)(Wo + gB0 + k0);
        rB1 = *(const int4*)(Wo + gB1 + k0);
        compute(As + xa, Bs + xa);
        xa ^= 4096;
        *(int4*)(As + xa + wA0) = rA0;
        *(int4*)(As + xa + wA1) = rA1;
        *(int4*)(Bs + xa + wA0) = rB0;
        *(int4*)(Bs + xa + wA1) = rB1;
        __syncthreads();
    }
    compute(As + xa, Bs + xa);

    // epilogue: pre = proj + x(bf16); in-place safe (each elem: one thread, read-before-write)
#pragma unroll
    for (int i = 0; i < 4; ++i) {
#pragma unroll
        for (int j = 0; j < 4; ++j) {
            const int colg = n0 + wnBase + j * 16 + fr;
#pragma unroll
            for (int r = 0; r < 4; ++r) {
                const int rowg = m0 + wmBase + i * 16 + quad * 4 + r;
                float pre = acc[i][j][r] + bf16_to_f32(Xb[rowg * DM + colg]);
                preout[rowg * DM + colg] = f32_to_bf16(pre);
            }
        }
    }
}

// ---------------- LayerNorm over rows of 1024 ----------------
__global__ __launch_bounds__(256) void ln_rows(const ushort_t* __restrict__ pre,
                                               const float* __restrict__ gamma,
                                               const float* __restrict__ beta,
                                               float* __restrict__ out)
{
    const int row = blockIdx.x;
    const int tid = threadIdx.x;
    const int wave = tid >> 6, lane = tid & 63;

    ushort4 u = ((const ushort4*)(pre + row * DM))[tid];
    float p0 = bf16_to_f32(u.x), p1 = bf16_to_f32(u.y);
    float p2 = bf16_to_f32(u.z), p3 = bf16_to_f32(u.w);

    float s  = p0 + p1 + p2 + p3;
    float ss = p0 * p0 + p1 * p1 + p2 * p2 + p3 * p3;
#pragma unroll
    for (int off = 32; off > 0; off >>= 1) {
        s  += __shfl_down(s, off);
        ss += __shfl_down(ss, off);
    }
    __shared__ float red[8];
    __shared__ float mb[2];
    if (lane == 0) { red[wave] = s; red[4 + wave] = ss; }
    __syncthreads();
    if (tid == 0) {
        float S  = red[0] + red[1] + red[2] + red[3];
        float SS = red[4] + red[5] + red[6] + red[7];
        float mean = S * (1.0f / 1024.0f);
        float var  = SS * (1.0f / 1024.0f) - mean * mean;
        mb[0] = mean;
        mb[1] = rsqrtf(var + 1e-5f);
    }
    __syncthreads();
    const float mean = mb[0], rs = mb[1];

    float4 gm = ((const float4*)gamma)[tid];
    float4 bt = ((const float4*)beta)[tid];
    float4 o;
    o.x = (p0 - mean) * rs * gm.x + bt.x;
    o.y = (p1 - mean) * rs * gm.y + bt.y;
    o.z = (p2 - mean) * rs * gm.z + bt.z;
    o.w = (p3 - mean) * rs * gm.w + bt.w;
    ((float4*)(out + row * DM))[tid] = o;
}

// ---------------- launch ----------------
extern "C" void kernel_launch(void* const* d_in, const int* in_sizes, int n_in,
                              void* d_out, int out_size, void* d_ws, size_t ws_size,
                              hipStream_t stream) {
    // setup_inputs order: x, W_Q, W_K, W_V, W_g, W_alpha, W_O, ln_gamma, ln_beta
    const float* x     = (const float*)d_in[0];
    const float* WV    = (const float*)d_in[3];
    const float* WG    = (const float*)d_in[4];
    const float* WO    = (const float*)d_in[6];
    const float* gamma = (const float*)d_in[7];
    const float* beta  = (const float*)d_in[8];
    float* out = (float*)d_out;

    // ws layout: [0,32MB): x_bf16 (later aliased as pre) | [32,64MB): gated | [64MB..): weights bf16
    char* ws = (char*)d_ws;
    ushort_t* xb    = (ushort_t*)ws;
    ushort_t* gated = (ushort_t*)(ws + (size_t)M_TOT * DM * 2);
    ushort_t* wvb   = (ushort_t*)(ws + (size_t)M_TOT * DM * 4);
    ushort_t* wgb   = (ushort_t*)(ws + (size_t)M_TOT * DM * 4 + (size_t)DM * DM * 2);
    ushort_t* wob   = (ushort_t*)(ws + (size_t)M_TOT * DM * 4 + (size_t)DM * DM * 4);
    ushort_t* pre   = xb;  // alias: in-place residual+store in gemm_o

    const int nCvt = (M_TOT * DM + 3 * DM * DM) / 4 / 256;
    cvt_all<<<nCvt, 256, 0, stream>>>(x, WV, WG, WO, xb, wvb, wgb, wob);

    gemm_vg<<<2048, 256, 0, stream>>>(xb, wvb, wgb, gated);
    gemm_o <<<1024, 256, 0, stream>>>(gated, wob, xb, pre);
    ln_rows<<<M_TOT, 256, 0, stream>>>(pre, gamma, beta, out);
}